// Round 1
// baseline (495.071 us; speedup 1.0000x reference)
//
#include <hip/hip_runtime.h>
#include <math.h>

#define BSZ 32
#define NP  1024

// ---- workspace layout (float offsets) ----
#define OFF_ACC    0                       // 8 scalars:
                                           // acc[0]=sum(logR - S) both mats (ent axis2 numer)
                                           // acc[1]=sum S both mats
                                           // acc[2]=sum T*logC both mats (ent axis1 part)
                                           // acc[3]=corr huber sum
                                           // acc[4]=chamfer min sum
#define OFF_COS    8                       // dot[32], n1[32], n2[32]
#define OFF_COLC1  104
#define OFF_COLT1  (OFF_COLC1 + 32768)
#define OFF_COLC2  (OFF_COLC1 + 65536)
#define OFF_COLT2  (OFF_COLC1 + 98304)
#define ZERO_FLOATS (OFF_COLC1 + 131072)   // 131176 floats zeroed
#define OFF_MIN    ZERO_FLOATS             // 131072 floats, memset 0x7f (=3.39e38)
#define OFF_POSE   (OFF_MIN + 131072)      // 24 floats per batch
#define OFF_P1TO2  (OFF_POSE + 768)
#define OFF_P2TO1  (OFF_P1TO2 + 98304)
#define OFF_P1IN2  (OFF_P2TO1 + 98304)
#define OFF_P2IN1  (OFF_P1IN2 + 98304)

// ---------------- pose: sRt and its inverse (adjugate) ----------------
__global__ void k_pose(const float* __restrict__ scale,
                       const float* __restrict__ rot,
                       const float* __restrict__ tr,
                       float* __restrict__ pose) {
    int b = threadIdx.x;
    if (b >= BSZ) return;
    float s = scale[b];
    float M[9];
#pragma unroll
    for (int i = 0; i < 9; ++i) M[i] = rot[b * 9 + i] * s;
    float t0 = tr[b * 3 + 0], t1 = tr[b * 3 + 1], t2 = tr[b * 3 + 2];
    float det = M[0] * (M[4] * M[8] - M[5] * M[7])
              - M[1] * (M[3] * M[8] - M[5] * M[6])
              + M[2] * (M[3] * M[7] - M[4] * M[6]);
    float id = 1.0f / det;
    float inv[9];
    inv[0] =  (M[4] * M[8] - M[5] * M[7]) * id;
    inv[1] = -(M[1] * M[8] - M[2] * M[7]) * id;
    inv[2] =  (M[1] * M[5] - M[2] * M[4]) * id;
    inv[3] = -(M[3] * M[8] - M[5] * M[6]) * id;
    inv[4] =  (M[0] * M[8] - M[2] * M[6]) * id;
    inv[5] = -(M[0] * M[5] - M[2] * M[3]) * id;
    inv[6] =  (M[3] * M[7] - M[4] * M[6]) * id;
    inv[7] = -(M[0] * M[7] - M[1] * M[6]) * id;
    inv[8] =  (M[0] * M[4] - M[1] * M[3]) * id;
    float u0 = -(inv[0] * t0 + inv[1] * t1 + inv[2] * t2);
    float u1 = -(inv[3] * t0 + inv[4] * t1 + inv[5] * t2);
    float u2 = -(inv[6] * t0 + inv[7] * t1 + inv[8] * t2);
    float* P = pose + b * 24;
#pragma unroll
    for (int i = 0; i < 9; ++i) P[i] = M[i];
    P[9] = t0; P[10] = t1; P[11] = t2;
#pragma unroll
    for (int i = 0; i < 9; ++i) P[12 + i] = inv[i];
    P[21] = u0; P[22] = u1; P[23] = u2;
}

// ---------------- transform points by pose / inverse pose ----------------
__global__ void k_transform(const float* __restrict__ p1, const float* __restrict__ p2,
                            const float* __restrict__ pose,
                            float* __restrict__ p1to2, float* __restrict__ p2to1) {
    int idx = blockIdx.x * 256 + threadIdx.x;   // 32*1024
    int b = idx >> 10;
    const float* P = pose + b * 24;
    float x = p1[idx * 3 + 0], y = p1[idx * 3 + 1], z = p1[idx * 3 + 2];
    p1to2[idx * 3 + 0] = P[0] * x + P[1] * y + P[2] * z + P[9];
    p1to2[idx * 3 + 1] = P[3] * x + P[4] * y + P[5] * z + P[10];
    p1to2[idx * 3 + 2] = P[6] * x + P[7] * y + P[8] * z + P[11];
    x = p2[idx * 3 + 0]; y = p2[idx * 3 + 1]; z = p2[idx * 3 + 2];
    p2to1[idx * 3 + 0] = P[12] * x + P[13] * y + P[14] * z + P[21];
    p2to1[idx * 3 + 1] = P[15] * x + P[16] * y + P[17] * z + P[22];
    p2to1[idx * 3 + 2] = P[18] * x + P[19] * y + P[20] * z + P[23];
}

// ---------------- the big fused pass over both assign matrices ----------------
// grid: 32 batches * 16 rowblocks = 512 blocks, 256 threads (4 waves, 16 rows/wave)
__global__ __launch_bounds__(256) void k_big(
    const float* __restrict__ am1, const float* __restrict__ am2,
    const float* __restrict__ pts1, const float* __restrict__ pts2,
    float* __restrict__ p1in2, float* __restrict__ p2in1,
    float* __restrict__ colC1, float* __restrict__ colT1,
    float* __restrict__ colC2, float* __restrict__ colT2,
    float* __restrict__ cosacc, float* __restrict__ acc) {
    const int b  = blockIdx.x >> 4;
    const int rb = blockIdx.x & 15;
    const int wv = threadIdx.x >> 6;
    const int ln = threadIdx.x & 63;
    const int row0 = rb * 64 + wv * 16;

    // lane's 16 fixed columns: c = 256*j + 4*ln + k  (i = 4*j + k)
    float pA[16][3];   // points_2 at lane's columns (for sa1 @ points_2)
    float pB[16][3];   // points_1 at lane's columns (for sa2 @ points_1)
#pragma unroll
    for (int j = 0; j < 4; ++j)
#pragma unroll
        for (int k = 0; k < 4; ++k) {
            int c = 256 * j + 4 * ln + k;
            int i = 4 * j + k;
            pA[i][0] = pts2[(b * NP + c) * 3 + 0];
            pA[i][1] = pts2[(b * NP + c) * 3 + 1];
            pA[i][2] = pts2[(b * NP + c) * 3 + 2];
            pB[i][0] = pts1[(b * NP + c) * 3 + 0];
            pB[i][1] = pts1[(b * NP + c) * 3 + 1];
            pB[i][2] = pts1[(b * NP + c) * 3 + 2];
        }

    float C1[16], T1[16], C2[16], T2[16];
#pragma unroll
    for (int i = 0; i < 16; ++i) { C1[i] = 0.f; T1[i] = 0.f; C2[i] = 0.f; T2[i] = 0.f; }
    float dacc = 0.f, n1a = 0.f, n2a = 0.f, e2a = 0.f, sSa = 0.f;

    const float4* rA = (const float4*)(am1 + ((size_t)b * NP + row0) * NP);
    const float4* rB = (const float4*)(am2 + ((size_t)b * NP + row0) * NP);

#pragma unroll 1
    for (int r = 0; r < 16; ++r) {
        float4 a[4], c4[4];
#pragma unroll
        for (int j = 0; j < 4; ++j) {
            a[j]  = rA[(size_t)r * 256 + ln + 64 * j];
            c4[j] = rB[(size_t)r * 256 + ln + 64 * j];
        }
        // cos-loss partials (need both raw matrices)
#pragma unroll
        for (int j = 0; j < 4; ++j) {
            dacc += a[j].x * c4[j].x + a[j].y * c4[j].y + a[j].z * c4[j].z + a[j].w * c4[j].w;
            n1a  += a[j].x * a[j].x + a[j].y * a[j].y + a[j].z * a[j].z + a[j].w * a[j].w;
            n2a  += c4[j].x * c4[j].x + c4[j].y * c4[j].y + c4[j].z * c4[j].z + c4[j].w * c4[j].w;
        }
        // ---- matrix 1 ----
        {
            float R = 0.f, Su = 0.f, q0 = 0.f, q1 = 0.f, q2 = 0.f;
#pragma unroll
            for (int j = 0; j < 4; ++j) {
                float* e = (float*)&a[j];
#pragma unroll
                for (int k = 0; k < 4; ++k) {
                    int i = 4 * j + k;
                    float v  = e[k];
                    float ex = __expf(v);
                    R += ex; Su += ex * v;
                    q0 += ex * pA[i][0]; q1 += ex * pA[i][1]; q2 += ex * pA[i][2];
                    C1[i] += ex;
                    e[k] = ex;
                }
            }
#pragma unroll
            for (int m = 1; m < 64; m <<= 1) {
                R  += __shfl_xor(R, m);  Su += __shfl_xor(Su, m);
                q0 += __shfl_xor(q0, m); q1 += __shfl_xor(q1, m); q2 += __shfl_xor(q2, m);
            }
            float inv = 1.0f / R;
#pragma unroll
            for (int j = 0; j < 4; ++j) {
                float* e = (float*)&a[j];
#pragma unroll
                for (int k = 0; k < 4; ++k) T1[4 * j + k] += e[k] * inv;
            }
            float S = Su * inv;
            if (ln == 0) {
                e2a += __logf(R) - S;
                sSa += S;
                int row = b * NP + row0 + r;
                p1in2[row * 3 + 0] = q0 * inv;
                p1in2[row * 3 + 1] = q1 * inv;
                p1in2[row * 3 + 2] = q2 * inv;
            }
        }
        // ---- matrix 2 ----
        {
            float R = 0.f, Su = 0.f, q0 = 0.f, q1 = 0.f, q2 = 0.f;
#pragma unroll
            for (int j = 0; j < 4; ++j) {
                float* e = (float*)&c4[j];
#pragma unroll
                for (int k = 0; k < 4; ++k) {
                    int i = 4 * j + k;
                    float v  = e[k];
                    float ex = __expf(v);
                    R += ex; Su += ex * v;
                    q0 += ex * pB[i][0]; q1 += ex * pB[i][1]; q2 += ex * pB[i][2];
                    C2[i] += ex;
                    e[k] = ex;
                }
            }
#pragma unroll
            for (int m = 1; m < 64; m <<= 1) {
                R  += __shfl_xor(R, m);  Su += __shfl_xor(Su, m);
                q0 += __shfl_xor(q0, m); q1 += __shfl_xor(q1, m); q2 += __shfl_xor(q2, m);
            }
            float inv = 1.0f / R;
#pragma unroll
            for (int j = 0; j < 4; ++j) {
                float* e = (float*)&c4[j];
#pragma unroll
                for (int k = 0; k < 4; ++k) T2[4 * j + k] += e[k] * inv;
            }
            float S = Su * inv;
            if (ln == 0) {
                e2a += __logf(R) - S;
                sSa += S;
                int row = b * NP + row0 + r;
                p2in1[row * 3 + 0] = q0 * inv;
                p2in1[row * 3 + 1] = q1 * inv;
                p2in1[row * 3 + 2] = q2 * inv;
            }
        }
    }

    // flush per-lane column accumulators
#pragma unroll
    for (int j = 0; j < 4; ++j)
#pragma unroll
        for (int k = 0; k < 4; ++k) {
            int i = 4 * j + k;
            int o = b * NP + 256 * j + 4 * ln + k;
            atomicAdd(&colC1[o], C1[i]);
            atomicAdd(&colT1[o], T1[i]);
            atomicAdd(&colC2[o], C2[i]);
            atomicAdd(&colT2[o], T2[i]);
        }
#pragma unroll
    for (int m = 1; m < 64; m <<= 1) {
        dacc += __shfl_xor(dacc, m);
        n1a  += __shfl_xor(n1a, m);
        n2a  += __shfl_xor(n2a, m);
    }
    if (ln == 0) {
        atomicAdd(&cosacc[b], dacc);
        atomicAdd(&cosacc[32 + b], n1a);
        atomicAdd(&cosacc[64 + b], n2a);
        atomicAdd(&acc[0], e2a);
        atomicAdd(&acc[1], sSa);
    }
}

// ---------------- column finalize: sum T * log C ----------------
__global__ void k_cols(const float* __restrict__ colC1, const float* __restrict__ colT1,
                       const float* __restrict__ colC2, const float* __restrict__ colT2,
                       float* __restrict__ acc) {
    int idx = blockIdx.x * 256 + threadIdx.x;   // 65536
    float v;
    if (idx < 32768) v = colT1[idx] * __logf(colC1[idx]);
    else { int i2 = idx - 32768; v = colT2[i2] * __logf(colC2[i2]); }
#pragma unroll
    for (int m = 1; m < 64; m <<= 1) v += __shfl_xor(v, m);
    if ((threadIdx.x & 63) == 0) atomicAdd(&acc[2], v);
}

// ---------------- chamfer: per-chunk min via uint atomicMin ----------------
__global__ __launch_bounds__(256) void k_chamfer(
    const float* __restrict__ p1to2, const float* __restrict__ p1in2,
    const float* __restrict__ p2to1, const float* __restrict__ p2in1,
    float* __restrict__ minarr) {
    int blk   = blockIdx.x;        // 512 = pair(2) * dir(2) * b(32) * chunk(4)
    int chunk = blk & 3;
    int b     = (blk >> 2) & 31;
    int dir   = (blk >> 7) & 1;
    int pair  = blk >> 8;
    const float* X; const float* Y;
    if (pair == 0) { X = dir ? p1in2 : p1to2; Y = dir ? p1to2 : p1in2; }
    else           { X = dir ? p2in1 : p2to1; Y = dir ? p2to1 : p2in1; }
    __shared__ float ys[256 * 3];
    int t = threadIdx.x;
    int yi = b * NP + chunk * 256 + t;
    ys[t * 3 + 0] = Y[yi * 3 + 0];
    ys[t * 3 + 1] = Y[yi * 3 + 1];
    ys[t * 3 + 2] = Y[yi * 3 + 2];
    __syncthreads();
    float* marr = minarr + ((size_t)(pair * 2 + dir) * 32 + b) * NP;
    float x0[4], x1[4], x2[4], mn[4];
#pragma unroll
    for (int i = 0; i < 4; ++i) {
        int xi = b * NP + i * 256 + t;
        x0[i] = X[xi * 3 + 0]; x1[i] = X[xi * 3 + 1]; x2[i] = X[xi * 3 + 2];
        mn[i] = 3.0e38f;
    }
    for (int o = 0; o < 256; ++o) {
        float y0 = ys[o * 3 + 0], y1 = ys[o * 3 + 1], y2 = ys[o * 3 + 2];
#pragma unroll
        for (int i = 0; i < 4; ++i) {
            float d0 = x0[i] - y0, d1 = x1[i] - y1, d2 = x2[i] - y2;
            float d = d0 * d0 + d1 * d1 + d2 * d2;
            mn[i] = fminf(mn[i], d);
        }
    }
#pragma unroll
    for (int i = 0; i < 4; ++i)
        atomicMin((unsigned int*)&marr[i * 256 + t], __float_as_uint(mn[i]));
}

// ---------------- correspondence (Huber) loss ----------------
__global__ void k_corr(const float* __restrict__ p1in2, const float* __restrict__ p1to2,
                       const float* __restrict__ p2in1, const float* __restrict__ p2to1,
                       float* __restrict__ acc) {
    int idx = blockIdx.x * 256 + threadIdx.x;   // 65536
    const float* A; const float* P;
    int i = idx;
    if (i < 32768) { A = p1in2; P = p1to2; }
    else           { A = p2in1; P = p2to1; i -= 32768; }
    float s = 0.f;
#pragma unroll
    for (int d = 0; d < 3; ++d) {
        float df = fabsf(A[i * 3 + d] - P[i * 3 + d]);
        s += (df > 0.1f) ? (df - 0.05f) : (df * df * 5.0f);
    }
#pragma unroll
    for (int m = 1; m < 64; m <<= 1) s += __shfl_xor(s, m);
    if ((threadIdx.x & 63) == 0) atomicAdd(&acc[3], s);
}

// ---------------- sum chamfer mins ----------------
__global__ void k_minsum(const float* __restrict__ minarr, float* __restrict__ acc) {
    int idx = blockIdx.x * 256 + threadIdx.x;   // 131072
    float v = minarr[idx];
#pragma unroll
    for (int m = 1; m < 64; m <<= 1) v += __shfl_xor(v, m);
    if ((threadIdx.x & 63) == 0) atomicAdd(&acc[4], v);
}

// ---------------- finalize ----------------
__global__ void k_final(const float* __restrict__ acc, const float* __restrict__ cosacc,
                        float* __restrict__ out) {
    if (threadIdx.x != 0) return;
    const float invBN = 1.0f / 32768.0f;
    float ent2 = 1e-4f * acc[0] * invBN;
    float ent1 = 1e-4f * (acc[2] - acc[1]) * invBN;
    float corr = acc[3] * invBN;
    float cham = acc[4] * invBN;
    float cosl = 0.f;
    for (int b = 0; b < 32; ++b) {
        float dot = cosacc[b];
        float na = fmaxf(sqrtf(cosacc[32 + b]), 1e-8f);
        float nb = fmaxf(sqrtf(cosacc[64 + b]), 1e-8f);
        cosl += 1.0f - dot / (na * nb);
    }
    cosl *= (1.0f / 32.0f);
    out[0] = cham + corr + ent2 + ent1 + cosl;
}

extern "C" void kernel_launch(void* const* d_in, const int* in_sizes, int n_in,
                              void* d_out, int out_size, void* d_ws, size_t ws_size,
                              hipStream_t stream) {
    const float* p1    = (const float*)d_in[0];
    const float* p2    = (const float*)d_in[1];
    const float* am1   = (const float*)d_in[2];
    const float* am2   = (const float*)d_in[3];
    const float* scale = (const float*)d_in[4];
    const float* rot   = (const float*)d_in[5];
    const float* tr    = (const float*)d_in[6];

    float* ws = (float*)d_ws;
    float* acc    = ws + OFF_ACC;
    float* cosacc = ws + OFF_COS;
    float* colC1  = ws + OFF_COLC1;
    float* colT1  = ws + OFF_COLT1;
    float* colC2  = ws + OFF_COLC2;
    float* colT2  = ws + OFF_COLT2;
    float* minarr = ws + OFF_MIN;
    float* pose   = ws + OFF_POSE;
    float* p1to2  = ws + OFF_P1TO2;
    float* p2to1  = ws + OFF_P2TO1;
    float* p1in2  = ws + OFF_P1IN2;
    float* p2in1  = ws + OFF_P2IN1;

    hipMemsetAsync(ws, 0, ZERO_FLOATS * sizeof(float), stream);
    hipMemsetAsync(minarr, 0x7F, 131072 * sizeof(float), stream);   // 0x7f7f7f7f = 3.39e38

    k_pose<<<1, 64, 0, stream>>>(scale, rot, tr, pose);
    k_transform<<<128, 256, 0, stream>>>(p1, p2, pose, p1to2, p2to1);
    k_big<<<512, 256, 0, stream>>>(am1, am2, p1, p2, p1in2, p2in1,
                                   colC1, colT1, colC2, colT2, cosacc, acc);
    k_cols<<<256, 256, 0, stream>>>(colC1, colT1, colC2, colT2, acc);
    k_chamfer<<<512, 256, 0, stream>>>(p1to2, p1in2, p2to1, p2in1, minarr);
    k_corr<<<256, 256, 0, stream>>>(p1in2, p1to2, p2in1, p2to1, acc);
    k_minsum<<<512, 256, 0, stream>>>(minarr, acc);
    k_final<<<1, 64, 0, stream>>>(acc, cosacc, (float*)d_out);
}